// Round 5
// baseline (180.013 us; speedup 1.0000x reference)
//
#include <hip/hip_runtime.h>
#include <hip/hip_fp16.h>
#include <stdint.h>

// ---------------- problem constants ----------------
constexpr int B_  = 8, HM = 64, WM = 64, A_ = 42, CIN = 256, HIDN = 512;
constexpr int M_  = HM * WM * A_;          // 172032 anchors per image
constexpr int NA  = B_ * M_;               // 1376256 total anchors
constexpr int HALF = NA / 2;               // 688128 (threefry pairing)
constexpr int KK  = CIN * 9;               // 2304 (im2col K)
constexpr float POS_T = 0.5f;

// positives / per-GT max window (anchors in PIXEL units, GT in feature units)
constexpr int WINY = 10, WINX = 10, WPIX = WINY * WINX;
constexpr int PERIMG = A_ * WPIX;                         // 4200
constexpr int WBLK = (PERIMG + 511) / 512;                // 9 window blocks/image
constexpr int NMAXB = WBLK * B_;                          // 72

// r7 lesson: npix in (384,1024]; MAXPIX=1024 is the proven bound.
constexpr int MAXPOS = 4096, MAXSEL = 4096, MAXCAND = 16384, MAXTIE = 256;
constexpr int MAXPIX = 1024;
constexpr uint32_t VCAND = 16384u;   // candidate cut on 23-bit uniform; E[cand]=2688

// GEMM (MFMA): f16 16x16x32, block = 16px x 128oc x FULL K=2304, 8 waves,
// K split ACROSS WAVES (288 each), LDS f32 reduce + bias + relu -> f16 h.
// No PART buffer, no kReduce dispatch. Same 8 waves/CU as the proven v4.
constexpr int KCH = 288;                     // K per wave
constexpr int TFBLK = HALF / 512;            // 1344 threefry blocks @512
constexpr int WCVTB = (HIDN * KK / 4) / 512; // 576 blocks: W fp32 -> f16
constexpr int NBLK_TF = NMAXB + TFBLK + WCVTB;  // 1992 (kTF fused grid)

// ---------------- workspace layout (bytes) ----------------
constexpr size_t OFF_CTRL  = 0;                       // u32[64]; f32 accums at [16..18]
constexpr size_t OFF_BINS  = 256;                     // u32[128] -> 768
constexpr size_t OFF_MAXGT = 768;                     // i32[160] (f32 bits) -> 1408
constexpr size_t OFF_SLOT  = 2048;                    // i32[32768] -> 133120
constexpr size_t MS_END    = 133120;                  // memset region [0, 133120)
constexpr size_t OFF_PLIST = 133120;                  // i32[MAXPIX]
constexpr size_t OFF_POSL  = 137216;                  // u32[MAXPOS] packed (i | arg<<21)
constexpr size_t OFF_SELL  = 153600;                  // i32[MAXSEL]
constexpr size_t OFF_CAND  = 169984;                  // uint2[MAXCAND] -> 301056
constexpr size_t OFF_APATCH= 8689664;                 // f16[MAXPIX][KK] = 4.7MB
constexpr size_t OFF_WF16  = 13408256;                // f16[HIDN][KK] = 2.36MB -> 15767552
constexpr size_t OFF_HFIN  = 15767552;                // f16[MAXPIX][HIDN] = 1MB -> 16816128
// end = ~16.8 MB

// ctrl: 0 nPos, 1 nSel, 2 nPix, 3 nCand, 10 head done, 11 pos-block done; accums ctrl[16..18]
// R3 lesson: NO __threadfence storms (L2 writeback serializes globally, ~8ns each en masse).
// Cross-block control flow = device-scope atomics only (coherent point, no fence needed);
// bulk normal-store producer->consumer = kernel boundary only.

// ---------------- bf16 / f16 helpers ----------------
__device__ __forceinline__ unsigned short f2bf(float f) {
  uint32_t x = __float_as_uint(f);
  uint32_t r = x + 0x7FFFu + ((x >> 16) & 1u);
  return (unsigned short)(r >> 16);
}
__device__ __forceinline__ float bf2f(unsigned short h) {
  return __uint_as_float(((uint32_t)h) << 16);
}
__device__ __forceinline__ uint32_t f2h2(float a, float b) {
  return (uint32_t)__half_as_ushort(__float2half_rn(a)) |
         ((uint32_t)__half_as_ushort(__float2half_rn(b)) << 16);
}

typedef _Float16 h8v __attribute__((ext_vector_type(8)));
typedef float f4v __attribute__((ext_vector_type(4)));

// ---------------- helpers ----------------
__device__ __forceinline__ float iou_pair(float ay0, float ax0, float ay1, float ax1,
                                          float areaA, float g0, float g1, float g2, float g3,
                                          float areaG) {
#pragma clang fp contract(off)
  float ty = fmaxf(ay0, g0), tx = fmaxf(ax0, g1);
  float by = fminf(ay1, g2), bx = fminf(ax1, g3);
  float hy = by - ty; hy = fmaxf(hy, 0.f);
  float hx = bx - tx; hx = fmaxf(hx, 0.f);
  float inter = hy * hx;
  return inter / (areaA + areaG - inter);
}

__device__ __forceinline__ void anchor_box(const float* basef, int a, int y, int x,
                                           float& ay0, float& ax0, float& ay1, float& ax1,
                                           float& areaA) {
#pragma clang fp contract(off)
  double sy = 16.0 * (double)y, sx = 16.0 * (double)x;
  ay0 = (float)((double)basef[a * 4 + 0] + sy);
  ax0 = (float)((double)basef[a * 4 + 1] + sx);
  ay1 = (float)((double)basef[a * 4 + 2] + sy);
  ax1 = (float)((double)basef[a * 4 + 3] + sx);
  areaA = (ay1 - ay0) * (ax1 - ax0);
}

__device__ __forceinline__ void fill_base(float* sbase, int t) {
  if (t < 42) {
    const double SC[6] = {2.0, 2.5, 3.0, 3.5, 4.0, 5.0};
    const double RA[7] = {0.5, 1.5, 2.0, 2.5, 3.0, 3.5, 4.0};
    int si = t / 7, ri = t - si * 7;
    double h = 16.0 * SC[si] * sqrt(RA[ri]);
    double w = 16.0 * SC[si] * sqrt(1.0 / RA[ri]);
    sbase[t * 4 + 0] = (float)(8.0 - h / 2.0);
    sbase[t * 4 + 1] = (float)(8.0 - w / 2.0);
    sbase[t * 4 + 2] = (float)(8.0 + h / 2.0);
    sbase[t * 4 + 3] = (float)(8.0 + w / 2.0);
  }
}

__device__ __forceinline__ void fill_gt(const float* gt, int b, float* sg, float* sarea,
                                        unsigned* sval, int t) {
  if (t < 20) {
#pragma clang fp contract(off)
    float g4[4];
    for (int d = 0; d < 4; d++) {
      float v = gt[(b * 20 + t) * 4 + d];
      g4[d] = (v == -1.0f) ? -1.0f : v * 0.0625f;
    }
    unsigned valid = (g4[0] >= 0.0f) ? 1u : 0u;
    if (!valid) { g4[0] = 0.f; g4[1] = 0.f; g4[2] = 1.f; g4[3] = 1.f; }
    sg[t * 4 + 0] = g4[0]; sg[t * 4 + 1] = g4[1]; sg[t * 4 + 2] = g4[2]; sg[t * 4 + 3] = g4[3];
    sarea[t] = (g4[2] - g4[0]) * (g4[3] - g4[1]);
    sval[t] = valid;
  }
}

__device__ __forceinline__ void claim_pixel(char* ws, int pixg) {
  int* slotmap = (int*)(ws + OFF_SLOT);
  if (atomicCAS((unsigned*)&slotmap[pixg], 0u, 0xFFFFFFFFu) == 0u) {
    unsigned s = atomicAdd((unsigned*)(ws + OFF_CTRL) + 2, 1u);
    if (s < MAXPIX) { ((int*)(ws + OFF_PLIST))[s] = pixg; slotmap[pixg] = (int)s + 1; }
    else slotmap[pixg] = -1;
  }
}

__device__ __forceinline__ float softplusf(float x) {
  return fmaxf(x, 0.f) + log1pf(expf(-fabsf(x)));
}
__device__ __forceinline__ float sl1(float d) {
  float ad = fabsf(d);
  return ad < 1.f ? 0.5f * ad * ad : ad - 0.5f;
}

__device__ __forceinline__ void tf_round(uint32_t& x0, uint32_t& x1, int r) {
  x0 += x1; x1 = (x1 << r) | (x1 >> (32 - r)); x1 ^= x0;
}
__device__ __forceinline__ void threefry(uint32_t c0, uint32_t c1, uint32_t& o0, uint32_t& o1) {
  const uint32_t k0 = 0u, k1 = 7u;
  const uint32_t k2 = k0 ^ k1 ^ 0x1BD11BDAu;
  uint32_t x0 = c0 + k0, x1 = c1 + k1;
  tf_round(x0, x1, 13); tf_round(x0, x1, 15); tf_round(x0, x1, 26); tf_round(x0, x1, 6);
  x0 += k1; x1 += k2 + 1u;
  tf_round(x0, x1, 17); tf_round(x0, x1, 29); tf_round(x0, x1, 16); tf_round(x0, x1, 24);
  x0 += k2; x1 += k0 + 2u;
  tf_round(x0, x1, 13); tf_round(x0, x1, 15); tf_round(x0, x1, 26); tf_round(x0, x1, 6);
  x0 += k0; x1 += k1 + 3u;
  tf_round(x0, x1, 17); tf_round(x0, x1, 29); tf_round(x0, x1, 16); tf_round(x0, x1, 24);
  x0 += k1; x1 += k2 + 4u;
  tf_round(x0, x1, 13); tf_round(x0, x1, 15); tf_round(x0, x1, 26); tf_round(x0, x1, 6);
  x0 += k2; x1 += k0 + 5u;
  o0 = x0; o1 = x1;
}

// wave-aggregated candidate emit (one ctrl[3] atomic per wave with hits)
__device__ __forceinline__ void dev_threefry_emit(char* ws, int p, int lane) {
  uint32_t o0, o1; threefry((uint32_t)p, (uint32_t)(p + HALF), o0, o1);
  uint32_t v0 = o0 >> 9, v1 = o1 >> 9;
  unsigned* ctrl = (unsigned*)(ws + OFF_CTRL);
  unsigned* bins = (unsigned*)(ws + OFF_BINS);
  uint2* cand = (uint2*)(ws + OFF_CAND);
  bool h0 = v0 < VCAND, h1 = v1 < VCAND;
  unsigned long long m0 = __ballot(h0), m1 = __ballot(h1);
  if (m0 | m1) {
    int n0 = __popcll(m0);
    int leader = (int)__ffsll(m0 | m1) - 1;
    unsigned base = 0;
    if (lane == leader) base = atomicAdd(&ctrl[3], (unsigned)(n0 + __popcll(m1)));
    base = (unsigned)__shfl((int)base, leader, 64);
    unsigned long long below = (1ull << lane) - 1ull;
    if (h0) {
      unsigned s = base + (unsigned)__popcll(m0 & below);
      if (s < MAXCAND) cand[s] = make_uint2(v0, (unsigned)p);
      atomicAdd(&bins[v0 >> 7], 1u);
    }
    if (h1) {
      unsigned s = base + (unsigned)n0 + (unsigned)__popcll(m1 & below);
      if (s < MAXCAND) cand[s] = make_uint2(v1, (unsigned)(p + HALF));
      atomicAdd(&bins[v1 >> 7], 1u);
    }
  }
}

// ---------------- kTF: windowed per-GT max + threefry + W->f16 (no fences) ----------------
__global__ void __launch_bounds__(512) kTF(const float* __restrict__ gt,
                                           const float* __restrict__ w1, char* ws) {
  __shared__ float sbase[168], sg[80], sarea[20];
  __shared__ unsigned sval[20];
  __shared__ int smax[20];
  int t = threadIdx.x, lane = t & 63;
  if (blockIdx.x < NMAXB) {
    int b = blockIdx.x / WBLK, blk = blockIdx.x - b * WBLK;
    fill_base(sbase, t);
    fill_gt(gt, b, sg, sarea, sval, t);
    if (t < 20) smax[t] = 0;
    __syncthreads();
    int idx = blk * 512 + t;
    bool ok = idx < PERIMG;
    float ay0 = 0.f, ax0 = 0.f, ay1 = 0.f, ax1 = 0.f, areaA = 1.f;
    if (ok) {
      int a = idx / WPIX, pp = idx - a * WPIX;
      int y = pp / WINX, x = pp - y * WINX;
      anchor_box(sbase, a, y, x, ay0, ax0, ay1, ax1, areaA);
    }
#pragma unroll
    for (int n = 0; n < 20; n++) {
      float io = 0.f;
      if (ok && sval[n]) io = iou_pair(ay0, ax0, ay1, ax1, areaA,
                                       sg[n * 4], sg[n * 4 + 1], sg[n * 4 + 2],
                                       sg[n * 4 + 3], sarea[n]);
#pragma unroll
      for (int off = 32; off >= 1; off >>= 1) io = fmaxf(io, __shfl_xor(io, off, 64));
      if ((t & 63) == 0 && io > 0.f) atomicMax(&smax[n], __float_as_int(io));
    }
    __syncthreads();
    if (t < 20 && smax[t] != 0)
      atomicMax((int*)(ws + OFF_MAXGT) + b * 20 + t, smax[t]);
  } else if (blockIdx.x < NMAXB + TFBLK) {
    int p = ((int)blockIdx.x - NMAXB) * 512 + t;
    if (p < HALF) dev_threefry_emit(ws, p, lane);
  } else {
    // W fp32 -> f16 pre-convert
    int q = ((int)blockIdx.x - (NMAXB + TFBLK)) * 512 + t;
    float4 v = ((const float4*)w1)[q];
    uint2 o;
    o.x = f2h2(v.x, v.y);
    o.y = f2h2(v.z, v.w);
    ((uint2*)(ws + OFF_WF16))[q] = o;
  }
}

// ---------------- kPos2: positives + fence-free last-arrival selection ----------------
__global__ void __launch_bounds__(512) kPos2(const float* __restrict__ gt, char* ws) {
  __shared__ float sbase[168], sg[80], sarea[20], smg[20];
  __shared__ unsigned sval[20];
  __shared__ unsigned selbins[128];
  __shared__ uint2 ties[MAXTIE];
  __shared__ unsigned tcnt, s_r, s_ucut;
  __shared__ int s_icut, s_cutbin, s_last;
  int b = blockIdx.y, t = threadIdx.x, lane = t & 63;
  unsigned* ctrl = (unsigned*)(ws + OFF_CTRL);
  fill_base(sbase, t);
  fill_gt(gt, b, sg, sarea, sval, t);
  if (t < 20) smg[t] = __int_as_float(((int*)(ws + OFF_MAXGT))[b * 20 + t]);
  __syncthreads();
  int idx = blockIdx.x * 512 + t;
  bool pos = false;
  unsigned packv = 0;
  int pixg = 0;
  if (idx < PERIMG) {
    int a = idx / WPIX, pp = idx - a * WPIX;
    int y = pp / WINX, x = pp - y * WINX;
    float ay0, ax0, ay1, ax1, areaA;
    anchor_box(sbase, a, y, x, ay0, ax0, ay1, ax1, areaA);
    float best = -1.f; int arg = 0;
#pragma unroll
    for (int n = 0; n < 20; n++) {
      float io = 0.f;
      if (sval[n]) io = iou_pair(ay0, ax0, ay1, ax1, areaA,
                                 sg[n * 4], sg[n * 4 + 1], sg[n * 4 + 2],
                                 sg[n * 4 + 3], sarea[n]);
      if (io > best) { best = io; arg = n; }
      float mg = smg[n];
      pos = pos || ((io == mg) && (mg > 0.f)) || (io > POS_T);
    }
    if (pos) {
      int pix = y * 64 + x;
      int i = b * M_ + pix * 42 + a;
      packv = (unsigned)i | ((unsigned)arg << 21);
      pixg = b * 4096 + pix;
    }
  }
  unsigned long long mask = __ballot(pos);
  if (mask) {
    int leader = (int)__ffsll(mask) - 1;
    unsigned base = 0;
    if (lane == leader) base = atomicAdd(&ctrl[0], (unsigned)__popcll(mask));
    base = (unsigned)__shfl((int)base, leader, 64);
    if (pos) {
      unsigned slot = base + (unsigned)__popcll(mask & ((1ull << lane) - 1ull));
      if (slot < MAXPOS) ((unsigned*)(ws + OFF_POSL))[slot] = packv;
      claim_pixel(ws, pixg);
    }
  }
  // ---- fence-free last-arrival gate: __syncthreads drains each wave's atomics;
  // device-scope atomics are already coherent, so no __threadfence needed ----
  __syncthreads();
  if (t == 0) {
    unsigned r = __hip_atomic_fetch_add(&ctrl[11], 1u, __ATOMIC_RELAXED,
                                        __HIP_MEMORY_SCOPE_AGENT);
    s_last = (r == (unsigned)(WBLK * B_) - 1) ? 1 : 0;
  }
  __syncthreads();
  if (!s_last) return;
  // ---- selection body (512 threads of the last-arriving block) ----
  const uint2* cand = (const uint2*)(ws + OFF_CAND);
  unsigned P = min(__hip_atomic_load(&ctrl[0], __ATOMIC_RELAXED,
                                     __HIP_MEMORY_SCOPE_AGENT), (unsigned)MAXPOS);
  unsigned nc = min(__hip_atomic_load(&ctrl[3], __ATOMIC_RELAXED,
                                      __HIP_MEMORY_SCOPE_AGENT), (unsigned)MAXCAND);
  if (t < 128) selbins[t] = ((const unsigned*)(ws + OFF_BINS))[t];
  if (t == 0) tcnt = 0;
  __syncthreads();
  if (t == 0) {
    unsigned cum = 0; int c = 0;
    for (; c < 128; c++) { if (cum + selbins[c] >= P) break; cum += selbins[c]; }
    if (c == 128) c = 127;
    s_cutbin = c; s_r = (P > cum) ? (P - cum) : 0u;
  }
  __syncthreads();
  int cutbin = s_cutbin;
  for (unsigned j = t; j < nc; j += 512) {
    uint2 cj = cand[j];
    if ((int)(cj.x >> 7) == cutbin) {
      unsigned k = atomicAdd(&tcnt, 1u);
      if (k < MAXTIE) ties[k] = cj;
    }
  }
  __syncthreads();
  // parallel rank-select: cutoff = r-th smallest (by (u, idx)) among ties
  unsigned n = min(tcnt, (unsigned)MAXTIE);
  unsigned r = s_r; if (r > n) r = n;
  if (r == 0) {
    if (t == 0) { s_ucut = 0; s_icut = -1; }
  } else if (t < (int)n) {
    uint2 mine = ties[t];
    unsigned rank = 0;
    for (unsigned j = 0; j < n; j++) {
      uint2 o = ties[j];
      if (o.x < mine.x || (o.x == mine.x && (int)o.y < (int)mine.y)) rank++;
    }
    if (rank == r - 1) { s_ucut = mine.x; s_icut = (int)mine.y; }
  }
  __syncthreads();
  unsigned ucut = s_ucut; int icut = s_icut;
  unsigned total = (nc + 511u) & ~511u;
  for (unsigned j = t; j < total; j += 512) {
    bool sel = false; uint2 cj = make_uint2(0u, 0u);
    if (j < nc) {
      cj = cand[j];
      sel = (cj.x < ucut) || (cj.x == ucut && (int)cj.y <= icut);
    }
    unsigned long long m2 = __ballot(sel);
    if (m2) {
      int leader = (int)__ffsll(m2) - 1;
      unsigned base = 0;
      if (lane == leader) base = atomicAdd(&ctrl[1], (unsigned)__popcll(m2));
      base = (unsigned)__shfl((int)base, leader, 64);
      if (sel) {
        unsigned slot = base + (unsigned)__popcll(m2 & ((1ull << lane) - 1ull));
        if (slot < MAXSEL) {
          ((int*)(ws + OFF_SELL))[slot] = (int)cj.y;
          int bb = (int)cj.y / M_; int m = (int)cj.y - bb * M_;
          claim_pixel(ws, bb * 4096 + m / 42);
        }
      }
    }
  }
}

// ---------------- kIm2col: (pixel, k-chunk) blocks, emits f16 pairs ----------------
__global__ void __launch_bounds__(256) kIm2col(const float* __restrict__ fm, char* ws) {
  unsigned* ctrl = (unsigned*)(ws + OFF_CTRL);
  int npix = min((int)ctrl[2], MAXPIX);
  int blk = blockIdx.x;
  if (blk >= npix) return;
  int chunk = blockIdx.y;                    // 3 chunks of 384 uints (768 k-elems)
  int pixg = ((const int*)(ws + OFF_PLIST))[blk];
  int b = pixg >> 12, pix = pixg & 4095;
  int y = pix >> 6, x = pix & 63;
  uint32_t* Ap = (uint32_t*)(ws + OFF_APATCH) + (size_t)blk * (KK / 2);
  int u0 = chunk * 384;
  for (int u = u0 + threadIdx.x; u < u0 + 384; u += 256) {
    float v[2];
#pragma unroll
    for (int h = 0; h < 2; h++) {
      int k = 2 * u + h;
      int ic = k / 9, r = k - ic * 9;
      int dy = r / 3, dx = r - dy * 3;
      int yy = y + dy - 1, xx = x + dx - 1;
      float vv = 0.f;
      if (yy >= 0 && yy < 64 && xx >= 0 && xx < 64)
        vv = fm[(((size_t)b * CIN + ic) * 64 + yy) * 64 + xx];
      v[h] = vv;
    }
    Ap[u] = f2h2(v[0], v[1]);
  }
}

// ---------------- kGemm: 16px x 128oc x K2304 per block, 8 waves (K-split by wave),
// LDS f32 reduce + bias + relu -> f16 h. No partial buffer, no second pass. ----------------
__global__ void __launch_bounds__(512) kGemm(const float* __restrict__ b1, char* ws) {
  __shared__ float red[8][16][132];          // 67.6 KB, stride 132 breaks bank periodicity
  unsigned* ctrl = (unsigned*)(ws + OFF_CTRL);
  int npix = min((int)ctrl[2], MAXPIX);
  int strip = blockIdx.x, och = blockIdx.y;
  int px0 = strip * 16;
  if (px0 >= npix) return;
  int oc0 = och * 128;
  const _Float16* Ap = (const _Float16*)(ws + OFF_APATCH);
  const _Float16* Wf = (const _Float16*)(ws + OFF_WF16);
  int t = threadIdx.x, lane = t & 63, wv = t >> 6;   // wv = K-chunk owner (0..7)
  int kq = lane >> 4;                                 // k-subchunk of 8 within step
  int kb = wv * KCH;                                  // 288 K per wave
  const _Float16* Arow = Ap + (size_t)(px0 + (lane & 15)) * KK + kb + kq * 8;
  const _Float16* Wrow = Wf + (size_t)(oc0 + (lane & 15)) * KK + kb + kq * 8;
  f4v acc[8] = {};
#pragma unroll 3
  for (int s = 0; s < 9; s++) {               // 9 x K=32 = 288
    h8v a = *(const h8v*)(Arow + s * 32);
#pragma unroll
    for (int o = 0; o < 8; o++) {
      h8v bfr = *(const h8v*)(Wrow + (size_t)o * 16 * KK + s * 32);
      acc[o] = __builtin_amdgcn_mfma_f32_16x16x32_f16(a, bfr, acc[o], 0, 0, 0);
    }
  }
  // stash per-wave partials (C/D layout: row=(lane>>4)*4+r -> px, col=lane&15 -> oc)
#pragma unroll
  for (int o = 0; o < 8; o++) {
    int col = o * 16 + (lane & 15);
#pragma unroll
    for (int r = 0; r < 4; r++)
      red[wv][kq * 4 + r][col] = acc[o][r];
  }
  __syncthreads();
  // reduce 8 wave-partials + bias + relu -> f16 h (coalesced 8B stores)
  int row = t >> 5, colg = t & 31;            // 16 rows x 32 groups of 4 oc
  if (px0 + row < npix) {
    float s4[4];
#pragma unroll
    for (int j = 0; j < 4; j++) s4[j] = b1[oc0 + colg * 4 + j];
#pragma unroll
    for (int w = 0; w < 8; w++)
#pragma unroll
      for (int j = 0; j < 4; j++) s4[j] += red[w][row][colg * 4 + j];
#pragma unroll
    for (int j = 0; j < 4; j++) s4[j] = fmaxf(s4[j], 0.f);
    unsigned short* hf = (unsigned short*)(ws + OFF_HFIN);
    uint2 o2;
    o2.x = f2h2(s4[0], s4[1]);
    o2.y = f2h2(s4[2], s4[3]);
    *(uint2*)(hf + (size_t)(px0 + row) * HIDN + oc0 + colg * 4) = o2;
  }
}

// ---------------- kHead: f16 h + heads + loss (fence-free finish) ----------------
__global__ void __launch_bounds__(256) kHead(const float* __restrict__ gt,
                                             const float* __restrict__ cw,
                                             const float* __restrict__ cb,
                                             const float* __restrict__ rw,
                                             const float* __restrict__ rb,
                                             char* ws, float* out) {
  __shared__ float sbase[168], sg[640];
  __shared__ float sacc[3];
  int t = threadIdx.x;
  fill_base(sbase, t);
  if (t < 160) {
#pragma clang fp contract(off)
    float g4[4];
    for (int d = 0; d < 4; d++) {
      float v = gt[t * 4 + d];
      g4[d] = (v == -1.0f) ? -1.0f : v * 0.0625f;
    }
    if (!(g4[0] >= 0.0f)) { g4[0] = 0.f; g4[1] = 0.f; g4[2] = 1.f; g4[3] = 1.f; }
    sg[t * 4 + 0] = g4[0]; sg[t * 4 + 1] = g4[1];
    sg[t * 4 + 2] = g4[2]; sg[t * 4 + 3] = g4[3];
  }
  if (t < 3) sacc[t] = 0.f;
  __syncthreads();
  unsigned* ctrl = (unsigned*)(ws + OFF_CTRL);
  float* accum = (float*)(ctrl + 16);
  int np = min((int)ctrl[0], MAXPOS);
  int ns = min((int)ctrl[1], MAXSEL);
  int nent = np + ns;
  const unsigned* posl = (const unsigned*)(ws + OFF_POSL);
  const int* sell = (const int*)(ws + OFF_SELL);
  const int* slotmap = (const int*)(ws + OFF_SLOT);
  const unsigned short* hfin = (const unsigned short*)(ws + OFF_HFIN);
  int lane = t & 63;
  int gwave = blockIdx.x * 4 + (t >> 6);
  int nwaves = gridDim.x * 4;
  for (int e = gwave; e < nent; e += nwaves) {
    bool isPos = e < np;
    int i, arg = 0;
    if (isPos) { unsigned pck = posl[e]; i = (int)(pck & 0x1FFFFFu); arg = (int)(pck >> 21); }
    else i = sell[e - np];
    int b = i / M_; int m = i - b * M_;
    int pix = m / 42; int a = m - pix * 42;
    int y = pix >> 6, x = pix & 63;
    int slot = slotmap[b * 4096 + pix] - 1;
    if (slot < 0 || slot >= MAXPIX) continue;
    float h[8];
    {
      h8v hv = *(const h8v*)(hfin + (size_t)slot * HIDN + lane * 8);
#pragma unroll
      for (int j = 0; j < 8; j++) h[j] = (float)hv[j];
    }
    const float* cwr = cw + (size_t)a * HIDN + lane * 8;
    float4 cA = *(const float4*)cwr;
    float4 cB = *(const float4*)(cwr + 4);
    float cp = h[0] * cA.x + h[1] * cA.y + h[2] * cA.z + h[3] * cA.w +
               h[4] * cB.x + h[5] * cB.y + h[6] * cB.z + h[7] * cB.w;
#pragma unroll
    for (int off = 32; off >= 1; off >>= 1) cp += __shfl_xor(cp, off, 64);
    float conf = cp + cb[a];
    if (isPos) {
      float rp[4];
#pragma unroll
      for (int d = 0; d < 4; d++) {
        const float* rwr = rw + (size_t)(a * 4 + d) * HIDN + lane * 8;
        float4 rA = *(const float4*)rwr;
        float4 rB = *(const float4*)(rwr + 4);
        float sd = h[0] * rA.x + h[1] * rA.y + h[2] * rA.z + h[3] * rA.w +
                   h[4] * rB.x + h[5] * rB.y + h[6] * rB.z + h[7] * rB.w;
#pragma unroll
        for (int off = 32; off >= 1; off >>= 1) sd += __shfl_xor(sd, off, 64);
        rp[d] = sd + rb[a * 4 + d];
      }
      if (lane == 0) {
#pragma clang fp contract(off)
        float ay0, ax0, ay1, ax1, areaA;
        anchor_box(sbase, a, y, x, ay0, ax0, ay1, ax1, areaA);
        const float* g = sg + (size_t)(b * 20 + arg) * 4;
        float acy = (ay0 + ay1) * 0.5f, acx = (ax0 + ax1) * 0.5f;
        float ah = ay1 - ay0, aw = ax1 - ax0;
        float gcy = (g[0] + g[2]) * 0.5f, gcx = (g[1] + g[3]) * 0.5f;
        float gh = g[2] - g[0], gw = g[3] - g[1];
        float t0 = (gcy - acy) / ah, t1 = (gcx - acx) / aw;
        float t2 = logf(gh / ah), t3 = logf(gw / aw);
        float sL = sl1(rp[0] - t0) + sl1(rp[1] - t1) + sl1(rp[2] - t2) + sl1(rp[3] - t3);
        atomicAdd(&sacc[2], sL);
        atomicAdd(&sacc[0], softplusf(-conf));
      }
    } else {
      if (lane == 0) atomicAdd(&sacc[1], softplusf(conf));
    }
  }
  __syncthreads();
  if (t == 0) {
    if (sacc[0] != 0.f) atomicAdd(&accum[0], sacc[0]);
    if (sacc[1] != 0.f) atomicAdd(&accum[1], sacc[1]);
    if (sacc[2] != 0.f) atomicAdd(&accum[2], sacc[2]);
    // fence-free finish: wait own atomics complete at L2, then count done
    asm volatile("s_waitcnt vmcnt(0)" ::: "memory");
    unsigned done = __hip_atomic_fetch_add(&ctrl[10], 1u, __ATOMIC_RELAXED,
                                           __HIP_MEMORY_SCOPE_AGENT);
    if (done == gridDim.x - 1) {
      float a0 = __hip_atomic_load(&accum[0], __ATOMIC_RELAXED, __HIP_MEMORY_SCOPE_AGENT);
      float a1 = __hip_atomic_load(&accum[1], __ATOMIC_RELAXED, __HIP_MEMORY_SCOPE_AGENT);
      float a2 = __hip_atomic_load(&accum[2], __ATOMIC_RELAXED, __HIP_MEMORY_SCOPE_AGENT);
      float P = (float)min((int)ctrl[0], MAXPOS);
      float S = (float)min((int)ctrl[1], MAXSEL);
      float cls = 0.5f * (a0 / P + a1 / S);
      out[0] = cls + a2 / (P * 4.0f);
    }
  }
}

// ---------------- launcher ----------------
extern "C" void kernel_launch(void* const* d_in, const int* in_sizes, int n_in,
                              void* d_out, int out_size, void* d_ws, size_t ws_size,
                              hipStream_t stream) {
  const float* fm = (const float*)d_in[0];
  const float* gt = (const float*)d_in[1];
  const float* w1 = (const float*)d_in[3];
  const float* b1 = (const float*)d_in[4];
  const float* cw = (const float*)d_in[5];
  const float* cb = (const float*)d_in[6];
  const float* rw = (const float*)d_in[7];
  const float* rb = (const float*)d_in[8];
  char* ws = (char*)d_ws;
  float* out = (float*)d_out;

  hipMemsetAsync(ws, 0, MS_END, stream);
  kTF<<<NBLK_TF, 512, 0, stream>>>(gt, w1, ws);
  kPos2<<<dim3(WBLK, B_), 512, 0, stream>>>(gt, ws);
  kIm2col<<<dim3(MAXPIX, 3), 256, 0, stream>>>(fm, ws);
  kGemm<<<dim3(MAXPIX / 16, 4), 512, 0, stream>>>(b1, ws);
  kHead<<<256, 256, 0, stream>>>(gt, cw, cb, rw, rb, ws, out);
}

// Round 6
// 162.645 us; speedup vs baseline: 1.1068x; 1.1068x over previous
//
#include <hip/hip_runtime.h>
#include <hip/hip_fp16.h>
#include <stdint.h>

// ---------------- problem constants ----------------
constexpr int B_  = 8, HM = 64, WM = 64, A_ = 42, CIN = 256, HIDN = 512;
constexpr int M_  = HM * WM * A_;          // 172032 anchors per image
constexpr int NA  = B_ * M_;               // 1376256 total anchors
constexpr int HALF = NA / 2;               // 688128 (threefry pairing)
constexpr int KK  = CIN * 9;               // 2304 (im2col K)
constexpr float POS_T = 0.5f;

// positives / per-GT max window (anchors in PIXEL units, GT in feature units)
constexpr int WINY = 10, WINX = 10, WPIX = WINY * WINX;
constexpr int PERIMG = A_ * WPIX;                         // 4200
constexpr int WBLK = (PERIMG + 511) / 512;                // 9 window blocks/image
constexpr int NMAXB = WBLK * B_;                          // 72

// r7 lesson: npix in (384,1024]; MAXPIX=1024 is the proven bound.
constexpr int MAXPOS = 4096, MAXSEL = 4096;
constexpr int MAXPIX = 1024;
constexpr uint32_t VCAND = 16384u;   // candidate cut on 23-bit uniform; E[cand]=2688
constexpr int NBIN = 128, CAP = 96;  // per-bin buckets; E=21/bin (data-independent), 96 = +16 sigma

// GEMM (MFMA): f16 16x16x32, block = 16px x 128oc x FULL K=2304, 8 waves,
// K split ACROSS WAVES (288 each), LDS f32 reduce + bias + relu -> f16 h.
constexpr int KCH = 288;                     // K per wave

// kTF fat-block grid (R5 lesson: ~16k tiny waves cost ~40us of pure launch/ramp
// overhead; grid-stride fat blocks amortize it)
constexpr int NWIN = NMAXB;                  // 72 window blocks
constexpr int NRND = 168;                    // threefry: 168 blk x 512 thr x 8 p = 688128
constexpr int NWCV = 72;                     // W-cvt: 72 blk x 512 thr x 8 quads = 294912
constexpr int NBLK_TF = NWIN + NRND + NWCV;  // 312

// ---------------- workspace layout (bytes) ----------------
constexpr size_t OFF_CTRL  = 0;                       // u32[64]; f32 accums at [16..18]
constexpr size_t OFF_MAXGT = 256;                     // i32[160] (f32 bits) -> 896
constexpr size_t OFF_BINSP = 1024;                    // u32[128*16] padded counters -> 9216
constexpr size_t OFF_SLOT  = 9216;                    // i32[32768] -> 140288
constexpr size_t MS_END    = 140288;                  // memset region [0, 140288)
constexpr size_t OFF_PLIST = 140288;                  // i32[MAXPIX]
constexpr size_t OFF_POSL  = 144384;                  // u32[MAXPOS] packed (i | arg<<21)
constexpr size_t OFF_SELL  = 160768;                  // i32[MAXSEL]
constexpr size_t OFF_CAND  = 177152;                  // uint2[128][96] buckets -> 275456
constexpr size_t OFF_APATCH= 8689664;                 // f16[MAXPIX][KK] = 4.7MB
constexpr size_t OFF_WF16  = 13408256;                // f16[HIDN][KK] = 2.36MB -> 15767552
constexpr size_t OFF_HFIN  = 15767552;                // f16[MAXPIX][HIDN] = 1MB -> 16816128
// end = ~16.8 MB

// ctrl: 0 nPos, 1 nSel, 2 nPix, 10 head done, 11 pos-block done; accums ctrl[16..18]
// R3 lesson: NO __threadfence storms. Cross-block control = device-scope atomics only;
// bulk normal-store producer->consumer = kernel boundary only.

// ---------------- bf16 / f16 helpers ----------------
__device__ __forceinline__ unsigned short f2bf(float f) {
  uint32_t x = __float_as_uint(f);
  uint32_t r = x + 0x7FFFu + ((x >> 16) & 1u);
  return (unsigned short)(r >> 16);
}
__device__ __forceinline__ float bf2f(unsigned short h) {
  return __uint_as_float(((uint32_t)h) << 16);
}
__device__ __forceinline__ uint32_t f2h2(float a, float b) {
  return (uint32_t)__half_as_ushort(__float2half_rn(a)) |
         ((uint32_t)__half_as_ushort(__float2half_rn(b)) << 16);
}

typedef _Float16 h8v __attribute__((ext_vector_type(8)));
typedef float f4v __attribute__((ext_vector_type(4)));

// ---------------- helpers ----------------
__device__ __forceinline__ float iou_pair(float ay0, float ax0, float ay1, float ax1,
                                          float areaA, float g0, float g1, float g2, float g3,
                                          float areaG) {
#pragma clang fp contract(off)
  float ty = fmaxf(ay0, g0), tx = fmaxf(ax0, g1);
  float by = fminf(ay1, g2), bx = fminf(ax1, g3);
  float hy = by - ty; hy = fmaxf(hy, 0.f);
  float hx = bx - tx; hx = fmaxf(hx, 0.f);
  float inter = hy * hx;
  return inter / (areaA + areaG - inter);
}

__device__ __forceinline__ void anchor_box(const float* basef, int a, int y, int x,
                                           float& ay0, float& ax0, float& ay1, float& ax1,
                                           float& areaA) {
#pragma clang fp contract(off)
  double sy = 16.0 * (double)y, sx = 16.0 * (double)x;
  ay0 = (float)((double)basef[a * 4 + 0] + sy);
  ax0 = (float)((double)basef[a * 4 + 1] + sx);
  ay1 = (float)((double)basef[a * 4 + 2] + sy);
  ax1 = (float)((double)basef[a * 4 + 3] + sx);
  areaA = (ay1 - ay0) * (ax1 - ax0);
}

__device__ __forceinline__ void fill_base(float* sbase, int t) {
  if (t < 42) {
    const double SC[6] = {2.0, 2.5, 3.0, 3.5, 4.0, 5.0};
    const double RA[7] = {0.5, 1.5, 2.0, 2.5, 3.0, 3.5, 4.0};
    int si = t / 7, ri = t - si * 7;
    double h = 16.0 * SC[si] * sqrt(RA[ri]);
    double w = 16.0 * SC[si] * sqrt(1.0 / RA[ri]);
    sbase[t * 4 + 0] = (float)(8.0 - h / 2.0);
    sbase[t * 4 + 1] = (float)(8.0 - w / 2.0);
    sbase[t * 4 + 2] = (float)(8.0 + h / 2.0);
    sbase[t * 4 + 3] = (float)(8.0 + w / 2.0);
  }
}

__device__ __forceinline__ void fill_gt(const float* gt, int b, float* sg, float* sarea,
                                        unsigned* sval, int t) {
  if (t < 20) {
#pragma clang fp contract(off)
    float g4[4];
    for (int d = 0; d < 4; d++) {
      float v = gt[(b * 20 + t) * 4 + d];
      g4[d] = (v == -1.0f) ? -1.0f : v * 0.0625f;
    }
    unsigned valid = (g4[0] >= 0.0f) ? 1u : 0u;
    if (!valid) { g4[0] = 0.f; g4[1] = 0.f; g4[2] = 1.f; g4[3] = 1.f; }
    sg[t * 4 + 0] = g4[0]; sg[t * 4 + 1] = g4[1]; sg[t * 4 + 2] = g4[2]; sg[t * 4 + 3] = g4[3];
    sarea[t] = (g4[2] - g4[0]) * (g4[3] - g4[1]);
    sval[t] = valid;
  }
}

__device__ __forceinline__ void claim_pixel(char* ws, int pixg) {
  int* slotmap = (int*)(ws + OFF_SLOT);
  if (atomicCAS((unsigned*)&slotmap[pixg], 0u, 0xFFFFFFFFu) == 0u) {
    unsigned s = atomicAdd((unsigned*)(ws + OFF_CTRL) + 2, 1u);
    if (s < MAXPIX) { ((int*)(ws + OFF_PLIST))[s] = pixg; slotmap[pixg] = (int)s + 1; }
    else slotmap[pixg] = -1;
  }
}

__device__ __forceinline__ float softplusf(float x) {
  return fmaxf(x, 0.f) + log1pf(expf(-fabsf(x)));
}
__device__ __forceinline__ float sl1(float d) {
  float ad = fabsf(d);
  return ad < 1.f ? 0.5f * ad * ad : ad - 0.5f;
}

__device__ __forceinline__ void tf_round(uint32_t& x0, uint32_t& x1, int r) {
  x0 += x1; x1 = (x1 << r) | (x1 >> (32 - r)); x1 ^= x0;
}
__device__ __forceinline__ void threefry(uint32_t c0, uint32_t c1, uint32_t& o0, uint32_t& o1) {
  const uint32_t k0 = 0u, k1 = 7u;
  const uint32_t k2 = k0 ^ k1 ^ 0x1BD11BDAu;
  uint32_t x0 = c0 + k0, x1 = c1 + k1;
  tf_round(x0, x1, 13); tf_round(x0, x1, 15); tf_round(x0, x1, 26); tf_round(x0, x1, 6);
  x0 += k1; x1 += k2 + 1u;
  tf_round(x0, x1, 17); tf_round(x0, x1, 29); tf_round(x0, x1, 16); tf_round(x0, x1, 24);
  x0 += k2; x1 += k0 + 2u;
  tf_round(x0, x1, 13); tf_round(x0, x1, 15); tf_round(x0, x1, 26); tf_round(x0, x1, 6);
  x0 += k0; x1 += k1 + 3u;
  tf_round(x0, x1, 17); tf_round(x0, x1, 29); tf_round(x0, x1, 16); tf_round(x0, x1, 24);
  x0 += k1; x1 += k2 + 4u;
  tf_round(x0, x1, 13); tf_round(x0, x1, 15); tf_round(x0, x1, 26); tf_round(x0, x1, 6);
  x0 += k2; x1 += k0 + 5u;
  o0 = x0; o1 = x1;
}

// bucketed emit: padded per-bin counter (128 spread addresses, 64B apart) -> no
// hot same-address atomic, no ctrl[3]
__device__ __forceinline__ void emit_cand(char* ws, uint32_t v, uint32_t p) {
  if (v < VCAND) {
    unsigned bin = v >> 7;
    unsigned slot = atomicAdd((unsigned*)(ws + OFF_BINSP) + bin * 16, 1u);
    if (slot < (unsigned)CAP)
      ((uint2*)(ws + OFF_CAND))[bin * CAP + slot] = make_uint2(v, p);
  }
}

// ---------------- kTF: fat blocks — window max + threefry + W->f16 ----------------
__global__ void __launch_bounds__(512) kTF(const float* __restrict__ gt,
                                           const float* __restrict__ w1, char* ws) {
  __shared__ float sbase[168], sg[80], sarea[20];
  __shared__ unsigned sval[20];
  __shared__ int smax[20];
  int t = threadIdx.x;
  if (blockIdx.x < NWIN) {
    int b = blockIdx.x / WBLK, blk = blockIdx.x - b * WBLK;
    fill_base(sbase, t);
    fill_gt(gt, b, sg, sarea, sval, t);
    if (t < 20) smax[t] = 0;
    __syncthreads();
    int idx = blk * 512 + t;
    bool ok = idx < PERIMG;
    float ay0 = 0.f, ax0 = 0.f, ay1 = 0.f, ax1 = 0.f, areaA = 1.f;
    if (ok) {
      int a = idx / WPIX, pp = idx - a * WPIX;
      int y = pp / WINX, x = pp - y * WINX;
      anchor_box(sbase, a, y, x, ay0, ax0, ay1, ax1, areaA);
    }
#pragma unroll
    for (int n = 0; n < 20; n++) {
      float io = 0.f;
      if (ok && sval[n]) io = iou_pair(ay0, ax0, ay1, ax1, areaA,
                                       sg[n * 4], sg[n * 4 + 1], sg[n * 4 + 2],
                                       sg[n * 4 + 3], sarea[n]);
#pragma unroll
      for (int off = 32; off >= 1; off >>= 1) io = fmaxf(io, __shfl_xor(io, off, 64));
      if ((t & 63) == 0 && io > 0.f) atomicMax(&smax[n], __float_as_int(io));
    }
    __syncthreads();
    if (t < 20 && smax[t] != 0)
      atomicMax((int*)(ws + OFF_MAXGT) + b * 20 + t, smax[t]);
  } else if (blockIdx.x < NWIN + NRND) {
    // threefry grid-stride: 8 p per thread
    int p0 = ((int)blockIdx.x - NWIN) * 512 + t;
#pragma unroll
    for (int it = 0; it < 8; it++) {
      int p = p0 + it * (NRND * 512);
      uint32_t o0, o1; threefry((uint32_t)p, (uint32_t)(p + HALF), o0, o1);
      emit_cand(ws, o0 >> 9, (uint32_t)p);
      emit_cand(ws, o1 >> 9, (uint32_t)(p + HALF));
    }
  } else {
    // W fp32 -> f16 grid-stride: 8 float4 per thread
    int q0 = ((int)blockIdx.x - (NWIN + NRND)) * 512 + t;
#pragma unroll
    for (int it = 0; it < 8; it++) {
      int q = q0 + it * (NWCV * 512);
      float4 v = ((const float4*)w1)[q];
      uint2 o;
      o.x = f2h2(v.x, v.y);
      o.y = f2h2(v.z, v.w);
      ((uint2*)(ws + OFF_WF16))[q] = o;
    }
  }
}

// ---------------- kPos2: positives + fence-free last-arrival bucket selection ----------------
__global__ void __launch_bounds__(512) kPos2(const float* __restrict__ gt, char* ws) {
  __shared__ float sbase[168], sg[80], sarea[20], smg[20];
  __shared__ unsigned sval[20];
  __shared__ unsigned scnt[128];
  __shared__ unsigned s_r, s_ucut;
  __shared__ int s_icut, s_cutbin, s_last;
  int b = blockIdx.y, t = threadIdx.x, lane = t & 63;
  unsigned* ctrl = (unsigned*)(ws + OFF_CTRL);
  fill_base(sbase, t);
  fill_gt(gt, b, sg, sarea, sval, t);
  if (t < 20) smg[t] = __int_as_float(((int*)(ws + OFF_MAXGT))[b * 20 + t]);
  __syncthreads();
  int idx = blockIdx.x * 512 + t;
  bool pos = false;
  unsigned packv = 0;
  int pixg = 0;
  if (idx < PERIMG) {
    int a = idx / WPIX, pp = idx - a * WPIX;
    int y = pp / WINX, x = pp - y * WINX;
    float ay0, ax0, ay1, ax1, areaA;
    anchor_box(sbase, a, y, x, ay0, ax0, ay1, ax1, areaA);
    float best = -1.f; int arg = 0;
#pragma unroll
    for (int n = 0; n < 20; n++) {
      float io = 0.f;
      if (sval[n]) io = iou_pair(ay0, ax0, ay1, ax1, areaA,
                                 sg[n * 4], sg[n * 4 + 1], sg[n * 4 + 2],
                                 sg[n * 4 + 3], sarea[n]);
      if (io > best) { best = io; arg = n; }
      float mg = smg[n];
      pos = pos || ((io == mg) && (mg > 0.f)) || (io > POS_T);
    }
    if (pos) {
      int pix = y * 64 + x;
      int i = b * M_ + pix * 42 + a;
      packv = (unsigned)i | ((unsigned)arg << 21);
      pixg = b * 4096 + pix;
    }
  }
  unsigned long long mask = __ballot(pos);
  if (mask) {
    int leader = (int)__ffsll(mask) - 1;
    unsigned base = 0;
    if (lane == leader) base = atomicAdd(&ctrl[0], (unsigned)__popcll(mask));
    base = (unsigned)__shfl((int)base, leader, 64);
    if (pos) {
      unsigned slot = base + (unsigned)__popcll(mask & ((1ull << lane) - 1ull));
      if (slot < MAXPOS) ((unsigned*)(ws + OFF_POSL))[slot] = packv;
      claim_pixel(ws, pixg);
    }
  }
  // ---- fence-free last-arrival gate ----
  __syncthreads();
  if (t == 0) {
    unsigned r = __hip_atomic_fetch_add(&ctrl[11], 1u, __ATOMIC_RELAXED,
                                        __HIP_MEMORY_SCOPE_AGENT);
    s_last = (r == (unsigned)(WBLK * B_) - 1) ? 1 : 0;
  }
  __syncthreads();
  if (!s_last) return;
  // ---- bucket selection (512 threads of the last-arriving block) ----
  const uint2* bucket = (const uint2*)(ws + OFF_CAND);
  unsigned P = min(__hip_atomic_load(&ctrl[0], __ATOMIC_RELAXED,
                                     __HIP_MEMORY_SCOPE_AGENT), (unsigned)MAXPOS);
  if (t < 128)
    scnt[t] = min(__hip_atomic_load((unsigned*)(ws + OFF_BINSP) + t * 16,
                                    __ATOMIC_RELAXED, __HIP_MEMORY_SCOPE_AGENT),
                  (unsigned)CAP);
  __syncthreads();
  if (t == 0) {
    unsigned cum = 0; int c = 0;
    for (; c < 128; c++) { if (cum + scnt[c] >= P) break; cum += scnt[c]; }
    if (c == 128) c = 127;
    s_cutbin = c; s_r = (P > cum) ? (P - cum) : 0u;
  }
  __syncthreads();
  int cutbin = s_cutbin;
  unsigned n = scnt[cutbin];
  unsigned r = s_r; if (r > n) r = n;
  // parallel rank-select within the cut bin's bucket
  if (r == 0) {
    if (t == 0) { s_ucut = 0; s_icut = -1; }
  } else if (t < (int)n) {
    uint2 mine = bucket[cutbin * CAP + t];
    unsigned rank = 0;
    for (unsigned j = 0; j < n; j++) {
      uint2 o = bucket[cutbin * CAP + j];
      if (o.x < mine.x || (o.x == mine.x && (int)o.y < (int)mine.y)) rank++;
    }
    if (rank == r - 1) { s_ucut = mine.x; s_icut = (int)mine.y; }
  }
  __syncthreads();
  unsigned ucut = s_ucut; int icut = s_icut;
  // scatter: all bucket entries passing the global (u,idx) cut
  for (unsigned j = t; j < (unsigned)(NBIN * CAP); j += 512) {
    unsigned bin = j / CAP, k = j - bin * CAP;
    bool sel = false; uint2 cj = make_uint2(0u, 0u);
    if (k < scnt[bin]) {
      cj = bucket[j];
      sel = (cj.x < ucut) || (cj.x == ucut && (int)cj.y <= icut);
    }
    unsigned long long m2 = __ballot(sel);
    if (m2) {
      int leader = (int)__ffsll(m2) - 1;
      unsigned base = 0;
      if (lane == leader) base = atomicAdd(&ctrl[1], (unsigned)__popcll(m2));
      base = (unsigned)__shfl((int)base, leader, 64);
      if (sel) {
        unsigned slot = base + (unsigned)__popcll(m2 & ((1ull << lane) - 1ull));
        if (slot < MAXSEL) {
          ((int*)(ws + OFF_SELL))[slot] = (int)cj.y;
          int bb = (int)cj.y / M_; int m = (int)cj.y - bb * M_;
          claim_pixel(ws, bb * 4096 + m / 42);
        }
      }
    }
  }
}

// ---------------- kIm2col: grid-stride fat blocks, emits f16 pairs ----------------
__global__ void __launch_bounds__(256) kIm2col(const float* __restrict__ fm, char* ws) {
  unsigned* ctrl = (unsigned*)(ws + OFF_CTRL);
  int npix = min((int)ctrl[2], MAXPIX);
  int chunk = blockIdx.y;                    // 3 chunks of 384 uints (768 k-elems)
  int u0 = chunk * 384;
  for (int blk = blockIdx.x; blk < npix; blk += gridDim.x) {
    int pixg = ((const int*)(ws + OFF_PLIST))[blk];
    int b = pixg >> 12, pix = pixg & 4095;
    int y = pix >> 6, x = pix & 63;
    uint32_t* Ap = (uint32_t*)(ws + OFF_APATCH) + (size_t)blk * (KK / 2);
    for (int u = u0 + threadIdx.x; u < u0 + 384; u += 256) {
      float v[2];
#pragma unroll
      for (int h = 0; h < 2; h++) {
        int k = 2 * u + h;
        int ic = k / 9, r = k - ic * 9;
        int dy = r / 3, dx = r - dy * 3;
        int yy = y + dy - 1, xx = x + dx - 1;
        float vv = 0.f;
        if (yy >= 0 && yy < 64 && xx >= 0 && xx < 64)
          vv = fm[(((size_t)b * CIN + ic) * 64 + yy) * 64 + xx];
        v[h] = vv;
      }
      Ap[u] = f2h2(v[0], v[1]);
    }
  }
}

// ---------------- kGemm: 16px x 128oc x K2304 per block, 8 waves (K-split by wave),
// LDS f32 reduce + bias + relu -> f16 h ----------------
__global__ void __launch_bounds__(512) kGemm(const float* __restrict__ b1, char* ws) {
  __shared__ float red[8][16][132];          // 67.6 KB, stride 132 breaks bank periodicity
  unsigned* ctrl = (unsigned*)(ws + OFF_CTRL);
  int npix = min((int)ctrl[2], MAXPIX);
  int strip = blockIdx.x, och = blockIdx.y;
  int px0 = strip * 16;
  if (px0 >= npix) return;
  int oc0 = och * 128;
  const _Float16* Ap = (const _Float16*)(ws + OFF_APATCH);
  const _Float16* Wf = (const _Float16*)(ws + OFF_WF16);
  int t = threadIdx.x, lane = t & 63, wv = t >> 6;   // wv = K-chunk owner (0..7)
  int kq = lane >> 4;                                 // k-subchunk of 8 within step
  int kb = wv * KCH;                                  // 288 K per wave
  const _Float16* Arow = Ap + (size_t)(px0 + (lane & 15)) * KK + kb + kq * 8;
  const _Float16* Wrow = Wf + (size_t)(oc0 + (lane & 15)) * KK + kb + kq * 8;
  f4v acc[8] = {};
#pragma unroll 3
  for (int s = 0; s < 9; s++) {               // 9 x K=32 = 288
    h8v a = *(const h8v*)(Arow + s * 32);
#pragma unroll
    for (int o = 0; o < 8; o++) {
      h8v bfr = *(const h8v*)(Wrow + (size_t)o * 16 * KK + s * 32);
      acc[o] = __builtin_amdgcn_mfma_f32_16x16x32_f16(a, bfr, acc[o], 0, 0, 0);
    }
  }
  // stash per-wave partials (C/D layout: row=(lane>>4)*4+r -> px, col=lane&15 -> oc)
#pragma unroll
  for (int o = 0; o < 8; o++) {
    int col = o * 16 + (lane & 15);
#pragma unroll
    for (int r = 0; r < 4; r++)
      red[wv][kq * 4 + r][col] = acc[o][r];
  }
  __syncthreads();
  // reduce 8 wave-partials + bias + relu -> f16 h (coalesced 8B stores)
  int row = t >> 5, colg = t & 31;            // 16 rows x 32 groups of 4 oc
  if (px0 + row < npix) {
    float s4[4];
#pragma unroll
    for (int j = 0; j < 4; j++) s4[j] = b1[oc0 + colg * 4 + j];
#pragma unroll
    for (int w = 0; w < 8; w++)
#pragma unroll
      for (int j = 0; j < 4; j++) s4[j] += red[w][row][colg * 4 + j];
#pragma unroll
    for (int j = 0; j < 4; j++) s4[j] = fmaxf(s4[j], 0.f);
    unsigned short* hf = (unsigned short*)(ws + OFF_HFIN);
    uint2 o2;
    o2.x = f2h2(s4[0], s4[1]);
    o2.y = f2h2(s4[2], s4[3]);
    *(uint2*)(hf + (size_t)(px0 + row) * HIDN + oc0 + colg * 4) = o2;
  }
}

// ---------------- kHead: f16 h + heads + loss (fence-free finish) ----------------
__global__ void __launch_bounds__(256) kHead(const float* __restrict__ gt,
                                             const float* __restrict__ cw,
                                             const float* __restrict__ cb,
                                             const float* __restrict__ rw,
                                             const float* __restrict__ rb,
                                             char* ws, float* out) {
  __shared__ float sbase[168], sg[640];
  __shared__ float sacc[3];
  int t = threadIdx.x;
  fill_base(sbase, t);
  if (t < 160) {
#pragma clang fp contract(off)
    float g4[4];
    for (int d = 0; d < 4; d++) {
      float v = gt[t * 4 + d];
      g4[d] = (v == -1.0f) ? -1.0f : v * 0.0625f;
    }
    if (!(g4[0] >= 0.0f)) { g4[0] = 0.f; g4[1] = 0.f; g4[2] = 1.f; g4[3] = 1.f; }
    sg[t * 4 + 0] = g4[0]; sg[t * 4 + 1] = g4[1];
    sg[t * 4 + 2] = g4[2]; sg[t * 4 + 3] = g4[3];
  }
  if (t < 3) sacc[t] = 0.f;
  __syncthreads();
  unsigned* ctrl = (unsigned*)(ws + OFF_CTRL);
  float* accum = (float*)(ctrl + 16);
  int np = min((int)ctrl[0], MAXPOS);
  int ns = min((int)ctrl[1], MAXSEL);
  int nent = np + ns;
  const unsigned* posl = (const unsigned*)(ws + OFF_POSL);
  const int* sell = (const int*)(ws + OFF_SELL);
  const int* slotmap = (const int*)(ws + OFF_SLOT);
  const unsigned short* hfin = (const unsigned short*)(ws + OFF_HFIN);
  int lane = t & 63;
  int gwave = blockIdx.x * 4 + (t >> 6);
  int nwaves = gridDim.x * 4;
  for (int e = gwave; e < nent; e += nwaves) {
    bool isPos = e < np;
    int i, arg = 0;
    if (isPos) { unsigned pck = posl[e]; i = (int)(pck & 0x1FFFFFu); arg = (int)(pck >> 21); }
    else i = sell[e - np];
    int b = i / M_; int m = i - b * M_;
    int pix = m / 42; int a = m - pix * 42;
    int y = pix >> 6, x = pix & 63;
    int slot = slotmap[b * 4096 + pix] - 1;
    if (slot < 0 || slot >= MAXPIX) continue;
    float h[8];
    {
      h8v hv = *(const h8v*)(hfin + (size_t)slot * HIDN + lane * 8);
#pragma unroll
      for (int j = 0; j < 8; j++) h[j] = (float)hv[j];
    }
    const float* cwr = cw + (size_t)a * HIDN + lane * 8;
    float4 cA = *(const float4*)cwr;
    float4 cB = *(const float4*)(cwr + 4);
    float cp = h[0] * cA.x + h[1] * cA.y + h[2] * cA.z + h[3] * cA.w +
               h[4] * cB.x + h[5] * cB.y + h[6] * cB.z + h[7] * cB.w;
#pragma unroll
    for (int off = 32; off >= 1; off >>= 1) cp += __shfl_xor(cp, off, 64);
    float conf = cp + cb[a];
    if (isPos) {
      float rp[4];
#pragma unroll
      for (int d = 0; d < 4; d++) {
        const float* rwr = rw + (size_t)(a * 4 + d) * HIDN + lane * 8;
        float4 rA = *(const float4*)rwr;
        float4 rB = *(const float4*)(rwr + 4);
        float sd = h[0] * rA.x + h[1] * rA.y + h[2] * rA.z + h[3] * rA.w +
                   h[4] * rB.x + h[5] * rB.y + h[6] * rB.z + h[7] * rB.w;
#pragma unroll
        for (int off = 32; off >= 1; off >>= 1) sd += __shfl_xor(sd, off, 64);
        rp[d] = sd + rb[a * 4 + d];
      }
      if (lane == 0) {
#pragma clang fp contract(off)
        float ay0, ax0, ay1, ax1, areaA;
        anchor_box(sbase, a, y, x, ay0, ax0, ay1, ax1, areaA);
        const float* g = sg + (size_t)(b * 20 + arg) * 4;
        float acy = (ay0 + ay1) * 0.5f, acx = (ax0 + ax1) * 0.5f;
        float ah = ay1 - ay0, aw = ax1 - ax0;
        float gcy = (g[0] + g[2]) * 0.5f, gcx = (g[1] + g[3]) * 0.5f;
        float gh = g[2] - g[0], gw = g[3] - g[1];
        float t0 = (gcy - acy) / ah, t1 = (gcx - acx) / aw;
        float t2 = logf(gh / ah), t3 = logf(gw / aw);
        float sL = sl1(rp[0] - t0) + sl1(rp[1] - t1) + sl1(rp[2] - t2) + sl1(rp[3] - t3);
        atomicAdd(&sacc[2], sL);
        atomicAdd(&sacc[0], softplusf(-conf));
      }
    } else {
      if (lane == 0) atomicAdd(&sacc[1], softplusf(conf));
    }
  }
  __syncthreads();
  if (t == 0) {
    if (sacc[0] != 0.f) atomicAdd(&accum[0], sacc[0]);
    if (sacc[1] != 0.f) atomicAdd(&accum[1], sacc[1]);
    if (sacc[2] != 0.f) atomicAdd(&accum[2], sacc[2]);
    // fence-free finish: wait own atomics complete at L2, then count done
    asm volatile("s_waitcnt vmcnt(0)" ::: "memory");
    unsigned done = __hip_atomic_fetch_add(&ctrl[10], 1u, __ATOMIC_RELAXED,
                                           __HIP_MEMORY_SCOPE_AGENT);
    if (done == gridDim.x - 1) {
      float a0 = __hip_atomic_load(&accum[0], __ATOMIC_RELAXED, __HIP_MEMORY_SCOPE_AGENT);
      float a1 = __hip_atomic_load(&accum[1], __ATOMIC_RELAXED, __HIP_MEMORY_SCOPE_AGENT);
      float a2 = __hip_atomic_load(&accum[2], __ATOMIC_RELAXED, __HIP_MEMORY_SCOPE_AGENT);
      float P = (float)min((int)ctrl[0], MAXPOS);
      float S = (float)min((int)ctrl[1], MAXSEL);
      float cls = 0.5f * (a0 / P + a1 / S);
      out[0] = cls + a2 / (P * 4.0f);
    }
  }
}

// ---------------- launcher ----------------
extern "C" void kernel_launch(void* const* d_in, const int* in_sizes, int n_in,
                              void* d_out, int out_size, void* d_ws, size_t ws_size,
                              hipStream_t stream) {
  const float* fm = (const float*)d_in[0];
  const float* gt = (const float*)d_in[1];
  const float* w1 = (const float*)d_in[3];
  const float* b1 = (const float*)d_in[4];
  const float* cw = (const float*)d_in[5];
  const float* cb = (const float*)d_in[6];
  const float* rw = (const float*)d_in[7];
  const float* rb = (const float*)d_in[8];
  char* ws = (char*)d_ws;
  float* out = (float*)d_out;

  hipMemsetAsync(ws, 0, MS_END, stream);
  kTF<<<NBLK_TF, 512, 0, stream>>>(gt, w1, ws);
  kPos2<<<dim3(WBLK, B_), 512, 0, stream>>>(gt, ws);
  kIm2col<<<dim3(128, 3), 256, 0, stream>>>(fm, ws);
  kGemm<<<dim3(MAXPIX / 16, 4), 512, 0, stream>>>(b1, ws);
  kHead<<<256, 256, 0, stream>>>(gt, cw, cb, rw, rb, ws, out);
}